// Round 18
// baseline (253.941 us; speedup 1.0000x reference)
//
#include <hip/hip_runtime.h>

// Guided filter r=8 (K=17), eps=0.1, (8,3,1024,1024); f32 in / f32 out.
// V10: 64x32 tile, 512 threads, quad-interleaved arena [48 rows][97 f4]
// (74,496 B -> 2 blocks/CU = 16 waves/CU). Halo work 3.0 -> 2.25 units/px.
// rcp-folded ab math; all LDS maps bank-uniform at stride 97.
//
//   A : vertical 17-tap sliding sums {I,p,Ip,II} -> quads, 384 units
//       (96 cols x 4 chunks of 12 rows), 12 b128 writes each
//   B1: horizontal 17-sums, 384 units (48 rows x 8 blocks of 10 ab-cols),
//       26 b128 reads, slide window in 18 quads; write (a,b) pairs f4 0..39
//   B2: horizontal 17-sums of (a,b), 384 units (48 x 8 blocks of 8 hs-cols),
//       12 b128 reads; write (hsA,hsB) pairs f4 40..71
//   C : vertical 17-sums, 512 units (64 cols x 8 strips of 4 rows),
//       20 b64 reads + out = INV*fma(sa,I,sb)

#define TW 64
#define TH 32
#define AR 48
#define F4STR 97                   // float4 per row (1552 B row stride)
#define INV_AREA (1.0f / 289.0f)

__device__ __forceinline__ int refl1024(int v) {
    v = (v < 0) ? -v : v;
    v = (v > 1023) ? 2046 - v : v;
    if (v < 0) v = 0;
    if (v > 1023) v = 1023;
    return v;
}

__global__ __launch_bounds__(512) void gf_fused(
    const float* __restrict__ P, const float* __restrict__ I,
    float* __restrict__ O, int H, int W)
{
    __shared__ __align__(16) float4 S4[AR * F4STR];   // 74496 B
    float2* __restrict__ Sf2 = (float2*)S4;

    const int tid = threadIdx.x;
    const int tx0 = blockIdx.x * TW;
    const int ty0 = blockIdx.y * TH;
    const size_t plane = (size_t)blockIdx.z * H * W;
    const float* __restrict__ Ic = I + plane;
    const float* __restrict__ Pc = P + plane;

    // ---------------- Phase A: vertical sliding sums -> quads ---------------
    if (tid < 384) {
        const int chunk = tid / 96;                    // 0..3
        const int col   = tid - chunk * 96;            // vs col 0..95
        const int r0    = chunk * 12;
        const int gx    = refl1024(tx0 + col - 16);

        float vI[28], vP[28];
        #pragma unroll
        for (int j = 0; j < 28; ++j) {
            const int gy = refl1024(ty0 + r0 - 16 + j);
            const size_t g = (size_t)gy * W + gx;
            vI[j] = Ic[g];
            vP[j] = Pc[g];
        }
        float s0 = 0.f, s1 = 0.f, s2 = 0.f, s3 = 0.f;
        #pragma unroll
        for (int j = 0; j < 17; ++j) {
            s0 += vI[j]; s1 += vP[j];
            s2 += vI[j] * vP[j];
            s3 += vI[j] * vI[j];
        }
        S4[r0 * F4STR + col] = make_float4(s0, s1, s2, s3);
        #pragma unroll
        for (int o = 1; o < 12; ++o) {
            const float ni = vI[o + 16], oi = vI[o - 1];
            const float np_ = vP[o + 16], op_ = vP[o - 1];
            s0 += ni - oi;
            s1 += np_ - op_;
            s2 += ni * np_ - oi * op_;
            s3 += ni * ni - oi * oi;
            S4[(r0 + o) * F4STR + col] = make_float4(s0, s1, s2, s3);
        }
    }
    __syncthreads();

    // ---------------- Phase B1: horizontal sums -> a,b ----------------------
    // 384 units: row=(tid&7)+8*(tid>>6) (waves 0..5), blk=(tid>>3)&7,
    // ab cols blk*10..blk*10+9 (img col tx0+c-8); window vs quads [c, c+25].
    const int brow = (tid & 7) + ((tid >> 6) << 3);
    const int blk  = (tid >> 3) & 7;
    float oa[10], ob[10];
    if (tid < 384) {
        float k0l[9], k1l[9], k2l[9], k3l[9];
        float k0h[9], k1h[9], k2h[9], k3h[9];
        float s0 = 0.f, s1 = 0.f, s2 = 0.f, s3 = 0.f;
        #pragma unroll
        for (int j = 0; j < 26; ++j) {
            const float4 w = S4[brow * F4STR + blk * 10 + j];
            if (j < 17) { s0 += w.x; s1 += w.y; s2 += w.z; s3 += w.w; }
            if (j < 9)  { k0l[j] = w.x; k1l[j] = w.y; k2l[j] = w.z; k3l[j] = w.w; }
            if (j >= 17) {
                const int m = j - 17;
                k0h[m] = w.x; k1h[m] = w.y; k2h[m] = w.z; k3h[m] = w.w;
            }
        }
        #pragma unroll
        for (int o = 0; o < 10; ++o) {
            if (o) {
                s0 += k0h[o - 1] - k0l[o - 1];
                s1 += k1h[o - 1] - k1l[o - 1];
                s2 += k2h[o - 1] - k2l[o - 1];
                s3 += k3h[o - 1] - k3l[o - 1];
            }
            const float num = fmaf(289.0f, s2, -s0 * s1);
            const float den = fmaf(289.0f, s3, -s0 * s0) + 8352.1f; // 289^2*0.1
            const float av  = num * __builtin_amdgcn_rcpf(den);
            oa[o] = av;
            ob[o] = fmaf(-av, s0, s1) * INV_AREA;
        }
    }
    __syncthreads();
    if (tid < 384) {
        // (a,b) pairs over f4 cols 0..39 (5 per block)
        #pragma unroll
        for (int t = 0; t < 5; ++t)
            S4[brow * F4STR + blk * 5 + t] =
                make_float4(oa[2 * t], ob[2 * t], oa[2 * t + 1], ob[2 * t + 1]);
    }
    __syncthreads();

    // ---------------- Phase B2: horizontal sums of (a,b) -> hs pairs --------
    // 384 units: same row; blk covers hs cols blk*8..blk*8+7 (img tx0+x);
    // window ab cols [x, x+23] = f4 pairs blk*4 + t, t in [0,12).
    if (tid < 384) {
        float qa[24], qb[24];
        #pragma unroll
        for (int t = 0; t < 12; ++t) {
            const float4 w = S4[brow * F4STR + blk * 4 + t];
            qa[2 * t] = w.x;     qb[2 * t] = w.y;
            qa[2 * t + 1] = w.z; qb[2 * t + 1] = w.w;
        }
        float hsA[8], hsB[8];
        float sa = 0.f, sb = 0.f;
        #pragma unroll
        for (int j = 0; j < 17; ++j) { sa += qa[j]; sb += qb[j]; }
        hsA[0] = sa; hsB[0] = sb;
        #pragma unroll
        for (int o = 1; o < 8; ++o) {
            sa += qa[o + 16] - qa[o - 1];
            sb += qb[o + 16] - qb[o - 1];
            hsA[o] = sa; hsB[o] = sb;
        }
        // (hsA,hsB) pairs at f4 cols 40..71 (disjoint from ab 0..39)
        #pragma unroll
        for (int t = 0; t < 4; ++t)
            S4[brow * F4STR + 40 + blk * 4 + t] =
                make_float4(hsA[2 * t], hsB[2 * t], hsA[2 * t + 1], hsB[2 * t + 1]);
    }
    __syncthreads();

    // ---------------- Phase C: vertical sums + finale -----------------------
    // 512 units: ox = tid&63, oy0 = (tid>>6)*4 -> 4 px each.
    {
        const int ox  = tid & 63;
        const int oy0 = (tid >> 6) << 2;   // 0,4,...,28
        float ca[20], cb[20];
        #pragma unroll
        for (int j = 0; j < 20; ++j) {
            const float2 w = Sf2[(oy0 + j) * (F4STR * 2) + 80 + ox];
            ca[j] = w.x; cb[j] = w.y;
        }
        float sa = 0.f, sb = 0.f;
        #pragma unroll
        for (int j = 0; j < 17; ++j) { sa += ca[j]; sb += cb[j]; }
        #pragma unroll
        for (int o = 0; o < 4; ++o) {
            if (o) {
                sa += ca[o + 16] - ca[o - 1];
                sb += cb[o + 16] - cb[o - 1];
            }
            const size_t gp = (size_t)(ty0 + oy0 + o) * W + (tx0 + ox);
            O[plane + gp] = INV_AREA * fmaf(sa, Ic[gp], sb);
        }
    }
}

extern "C" void kernel_launch(void* const* d_in, const int* in_sizes, int n_in,
                              void* d_out, int out_size, void* d_ws, size_t ws_size,
                              hipStream_t stream) {
    const int H = 1024, W = 1024;
    if (n_in < 2) return;
    const long long npx = (long long)H * W;
    const long long n0 = in_sizes[0];
    if (n0 <= 0 || (n0 % npx) != 0) return;
    if ((long long)out_size != n0) return;
    if (in_sizes[1] != in_sizes[0]) return;
    const int NP = (int)(n0 / npx);

    const float* p = (const float*)d_in[0];   // input_img
    const float* I = (const float*)d_in[1];   // guide_img
    float* out = (float*)d_out;

    dim3 grid(W / TW, H / TH, NP);
    gf_fused<<<grid, 512, 0, stream>>>(p, I, out, H, W);
}

// Round 19
// 153.762 us; speedup vs baseline: 1.6515x; 1.6515x over previous
//
#include <hip/hip_runtime.h>

// Guided filter r=8 (K=17), eps=0.1, (8,3,1024,1024); f32 in / f32 out.
// V11 = R17 (quad-interleaved arena) + __launch_bounds__(256, 1).
// R18 post-mortem: hipcc's VGPR heuristic ignores the LDS occupancy cap
// (R16/R17: VGPR=68 while LDS caps at 3 blocks/CU = 3 waves/SIMD = 170-reg
// budget) and re-reads LDS instead of keeping B1's 28-quad slide window in
// registers. min-waves=1 lifts the cap to 512; expected use ~110-140, which
// keeps the same 3 blocks/CU (<=170) but removes the re-read traffic.
//
//   A : vertical 17-tap sliding sums {I,p,Ip,II} (28-row reg window)
//       -> quad per (row,col), 12 ds_write_b128
//   B1: horizontal 17-sums of quads (28 b128 reads, window in regs) -> a,b
//       via rcp-folded form; write (a,b) pairs over f4 cols 0..23
//   B2: horizontal 17-sums of (a,b) (12 b128) -> (hsA,hsB) pairs, f4 cols 40..55
//   C : vertical 17-sums of hs pairs (20 b64) + out = INV*fma(sa,I,sb)

#define TW 32
#define TH 32
#define AR 48
#define F4STR 65                   // float4 per row (1040 B row stride)
#define INV_AREA (1.0f / 289.0f)

__device__ __forceinline__ int refl1024(int v) {
    v = (v < 0) ? -v : v;
    v = (v > 1023) ? 2046 - v : v;
    if (v < 0) v = 0;
    if (v > 1023) v = 1023;
    return v;
}

__global__ __launch_bounds__(256, 1) void gf_fused(
    const float* __restrict__ P, const float* __restrict__ I,
    float* __restrict__ O, int H, int W)
{
    __shared__ __align__(16) float4 S4[AR * F4STR];   // 49920 B
    float2* __restrict__ Sf2 = (float2*)S4;

    const int tid = threadIdx.x;
    const int tx0 = blockIdx.x * TW;
    const int ty0 = blockIdx.y * TH;
    const size_t plane = (size_t)blockIdx.z * H * W;
    const float* __restrict__ Ic = I + plane;
    const float* __restrict__ Pc = P + plane;

    // ---------------- Phase A: vertical sliding sums -> quads ---------------
    {
        const int vc = tid & 63;                                   // vs col
        const int ck = __builtin_amdgcn_readfirstlane(tid >> 6);   // wave-uniform
        const int r0 = ck * 12;
        const int gx = refl1024(tx0 + vc - 16);

        float vI[28], vP[28];
        #pragma unroll
        for (int j = 0; j < 28; ++j) {
            const int gy = refl1024(ty0 + r0 - 16 + j);            // scalar
            const float* __restrict__ rI = Ic + (size_t)gy * W;    // SGPR base
            const float* __restrict__ rP = Pc + (size_t)gy * W;
            vI[j] = rI[gx];
            vP[j] = rP[gx];
        }
        float s0 = 0.f, s1 = 0.f, s2 = 0.f, s3 = 0.f;
        #pragma unroll
        for (int j = 0; j < 17; ++j) {
            s0 += vI[j]; s1 += vP[j];
            s2 += vI[j] * vP[j];
            s3 += vI[j] * vI[j];
        }
        S4[r0 * F4STR + vc] = make_float4(s0, s1, s2, s3);
        #pragma unroll
        for (int o = 1; o < 12; ++o) {
            const float ni = vI[o + 16], oi = vI[o - 1];
            const float np_ = vP[o + 16], op_ = vP[o - 1];
            s0 += ni - oi;
            s1 += np_ - op_;
            s2 += ni * np_ - oi * op_;
            s3 += ni * ni - oi * oi;
            S4[(r0 + o) * F4STR + vc] = make_float4(s0, s1, s2, s3);
        }
    }
    __syncthreads();

    // ---------------- Phase B1: horizontal sums -> a,b ----------------------
    const int vr = (tid & 15) + ((tid >> 6) << 4);   // 0..47 (tid<192)
    const int u4 = (tid >> 4) & 3;                   // col-block (12 ab cols)
    float oa[12], ob[12];
    if (tid < 192) {
        // keep only slide window: j in [0,10] (drop side) and [17,27] (add side)
        float k0l[11], k1l[11], k2l[11], k3l[11];
        float k0h[11], k1h[11], k2h[11], k3h[11];
        float s0 = 0.f, s1 = 0.f, s2 = 0.f, s3 = 0.f;
        #pragma unroll
        for (int j = 0; j < 28; ++j) {
            const float4 w = S4[vr * F4STR + u4 * 12 + j];
            if (j < 17) { s0 += w.x; s1 += w.y; s2 += w.z; s3 += w.w; }
            if (j < 11) { k0l[j] = w.x; k1l[j] = w.y; k2l[j] = w.z; k3l[j] = w.w; }
            if (j >= 17) {
                const int m = j - 17;
                k0h[m] = w.x; k1h[m] = w.y; k2h[m] = w.z; k3h[m] = w.w;
            }
        }
        #pragma unroll
        for (int o = 0; o < 12; ++o) {
            if (o) {
                s0 += k0h[o - 1] - k0l[o - 1];
                s1 += k1h[o - 1] - k1l[o - 1];
                s2 += k2h[o - 1] - k2l[o - 1];
                s3 += k3h[o - 1] - k3l[o - 1];
            }
            const float num = fmaf(289.0f, s2, -s0 * s1);
            const float den = fmaf(289.0f, s3, -s0 * s0) + 8352.1f; // 289^2*0.1
            const float av  = num * __builtin_amdgcn_rcpf(den);
            oa[o] = av;
            ob[o] = fmaf(-av, s0, s1) * INV_AREA;
        }
    }
    __syncthreads();
    if (tid < 192) {
        // (a,b) pairs over f4 cols 0..23: col pair (2t,2t+1) of this block
        #pragma unroll
        for (int t = 0; t < 6; ++t)
            S4[vr * F4STR + u4 * 6 + t] =
                make_float4(oa[2 * t], ob[2 * t], oa[2 * t + 1], ob[2 * t + 1]);
    }
    __syncthreads();

    // ---------------- Phase B2: horizontal sums of (a,b) -> hs pairs --------
    if (tid < 192) {
        float qa[24], qb[24];
        #pragma unroll
        for (int t = 0; t < 12; ++t) {
            const float4 w = S4[vr * F4STR + u4 * 4 + t];
            qa[2 * t] = w.x;     qb[2 * t] = w.y;
            qa[2 * t + 1] = w.z; qb[2 * t + 1] = w.w;
        }
        float hsA[8], hsB[8];
        float sa = 0.f, sb = 0.f;
        #pragma unroll
        for (int j = 0; j < 17; ++j) { sa += qa[j]; sb += qb[j]; }
        hsA[0] = sa; hsB[0] = sb;
        #pragma unroll
        for (int o = 1; o < 8; ++o) {
            sa += qa[o + 16] - qa[o - 1];
            sb += qb[o + 16] - qb[o - 1];
            hsA[o] = sa; hsB[o] = sb;
        }
        // (hsA,hsB) pairs at f4 cols 40..55 (disjoint from ab cols 0..23)
        #pragma unroll
        for (int t = 0; t < 4; ++t)
            S4[vr * F4STR + 40 + u4 * 4 + t] =
                make_float4(hsA[2 * t], hsB[2 * t], hsA[2 * t + 1], hsB[2 * t + 1]);
    }
    __syncthreads();

    // ---------------- Phase C: vertical sums + finale -----------------------
    {
        const int ox  = tid & 31;
        const int oy0 = (tid >> 5) * 4;    // 0,4,...,28
        float ca[20], cb[20];
        #pragma unroll
        for (int j = 0; j < 20; ++j) {
            const float2 w = Sf2[(oy0 + j) * (F4STR * 2) + 80 + ox];
            ca[j] = w.x; cb[j] = w.y;
        }
        float sa = 0.f, sb = 0.f;
        #pragma unroll
        for (int j = 0; j < 17; ++j) { sa += ca[j]; sb += cb[j]; }
        #pragma unroll
        for (int o = 0; o < 4; ++o) {
            if (o) {
                sa += ca[o + 16] - ca[o - 1];
                sb += cb[o + 16] - cb[o - 1];
            }
            const size_t gp = (size_t)(ty0 + oy0 + o) * W + (tx0 + ox);
            O[plane + gp] = INV_AREA * fmaf(sa, Ic[gp], sb);
        }
    }
}

extern "C" void kernel_launch(void* const* d_in, const int* in_sizes, int n_in,
                              void* d_out, int out_size, void* d_ws, size_t ws_size,
                              hipStream_t stream) {
    const int H = 1024, W = 1024;
    if (n_in < 2) return;
    const long long npx = (long long)H * W;
    const long long n0 = in_sizes[0];
    if (n0 <= 0 || (n0 % npx) != 0) return;
    if ((long long)out_size != n0) return;
    if (in_sizes[1] != in_sizes[0]) return;
    const int NP = (int)(n0 / npx);

    const float* p = (const float*)d_in[0];   // input_img
    const float* I = (const float*)d_in[1];   // guide_img
    float* out = (float*)d_out;

    dim3 grid(W / TW, H / TH, NP);
    gf_fused<<<grid, 256, 0, stream>>>(p, I, out, H, W);
}